// Round 1
// baseline (313.646 us; speedup 1.0000x reference)
//
#include <hip/hip_runtime.h>
#include <hip/hip_bf16.h>
#include <stdint.h>

// Problem: out[b,o] = sum_{l,i} lookups[b,l]*values[b,i]*W[l,i,o] + sum_l lookups[b,l]*bias[l,o]
// B=65536, L=16, I=256, O=256  -> GEMM M=65536, K=4096(+64 bias tile), N=256, bf16 MFMA.

#define B_TOK 65536
#define L_DIM 16
#define I_DIM 256
#define O_DIM 256
#define NKT   65          // 64 K-tiles of 64 + 1 bias tile
#define BK    64
#define BM    128
#define BN    256
#define THREADS 512

typedef __attribute__((ext_vector_type(8))) short bf16x8;
typedef __attribute__((ext_vector_type(4))) float f32x4;

typedef __attribute__((address_space(3))) void      lds_void_t;
typedef const __attribute__((address_space(1))) void gbl_void_t;

static __device__ __forceinline__ unsigned short f2bf(float f) {
    uint32_t u = __builtin_bit_cast(uint32_t, f);
    u += 0x7fffu + ((u >> 16) & 1u);   // RNE
    return (unsigned short)(u >> 16);
}

// ---------------------------------------------------------------------------
// Pre-kernel: build W_stage in ws: 65 tiles x 32KB bf16.
// Tile kt holds B-operand tile [o=0..255][kk=0..63] (o-major, k-minor = transposed W)
// at swizzled element index (o*64+kk) ^ ((o&7)<<3)  (byte ^ ((o&7)<<4)).
// Tiles 0..63: element = W[l][i][o] with k=kt*64+kk, l=k>>8, i=k&255.
// Tile 64 (bias): element = (kk<16) ? bias[kk][o] : 0.
// ---------------------------------------------------------------------------
__global__ void prep_w(const float* __restrict__ W, const float* __restrict__ bias,
                       __hip_bfloat16* __restrict__ ws) {
    int e = blockIdx.x * 256 + threadIdx.x;       // 65*16384 = 1064960 total
    if (e >= NKT * 16384) return;
    int kt  = e >> 14;
    int idx = e & 16383;
    int o   = idx & 255;        // fastest -> coalesced W reads
    int kk  = idx >> 8;         // 0..63
    float v;
    if (kt < 64) {
        int k = kt * 64 + kk;
        int l = k >> 8, i = k & 255;
        v = W[((size_t)l * I_DIM + i) * O_DIM + o];
    } else {
        v = (kk < 16) ? bias[kk * O_DIM + o] : 0.0f;
    }
    int swz = (o * 64 + kk) ^ ((o & 7) << 3);
    unsigned short h = f2bf(v);
    ((unsigned short*)ws)[(size_t)kt * 16384 + swz] = h;
}

// ---------------------------------------------------------------------------
// Main GEMM. grid = 512 blocks (M/128), 512 threads (8 waves, 2M x 4N wave grid).
// LDS per buffer: A[128][64] bf16 (16KB, XOR-swizzled) + B[256][64] bf16 (32KB,
// swizzled-in-global, staged linearly via global_load_lds). Double buffered: 96KB.
// ---------------------------------------------------------------------------
__launch_bounds__(THREADS, 2)
__global__ void md_gemm(const float* __restrict__ lookups,       // [B][16]
                        const float* __restrict__ values,        // [B][256]
                        const __hip_bfloat16* __restrict__ Wst,  // [65][16384] staged
                        float* __restrict__ out) {               // [B][256]
    __shared__ char smem[2 * (16384 + 32768)];   // 96KB

    const int tid  = threadIdx.x;
    const int wid  = tid >> 6;
    const int lane = tid & 63;
    const int row0 = blockIdx.x * BM;

    // A staging: thread owns row ar, 16 consecutive k at akk
    const int ar  = tid >> 2;            // 0..127
    const int akk = (tid & 3) * 16;      // 0/16/32/48

    // compute-side coords
    const int wm   = wid >> 2;           // 0..1 : M-wave
    const int wn   = wid & 3;            // 0..3 : N-wave
    const int arow = wm * 64 + (lane & 15);
    const int bcol = wn * 64 + (lane & 15);
    const int kkl  = (lane >> 4) * 8;

    f32x4 acc[4][4];
#pragma unroll
    for (int m = 0; m < 4; ++m)
#pragma unroll
        for (int n = 0; n < 4; ++n) acc[m][n] = (f32x4){0.f, 0.f, 0.f, 0.f};

    float4 av[4];
    float  sc = 0.f;

    auto stageB = [&](int kt, int bsel_) {
        const char* src = (const char*)Wst + (size_t)kt * 32768 + wid * 1024 + lane * 16;
        char* dst = smem + bsel_ * 49152 + 16384 + wid * 1024;  // wave-uniform base
#pragma unroll
        for (int s = 0; s < 4; ++s)
            __builtin_amdgcn_global_load_lds((gbl_void_t*)(src + s * 8192),
                                             (lds_void_t*)(dst + s * 8192), 16, 0, 0);
    };

    auto loadA = [&](int kt) {
        if (kt < 64) {
            const float* vp = values + (size_t)(row0 + ar) * I_DIM + (kt & 3) * 64 + akk;
#pragma unroll
            for (int j = 0; j < 4; ++j) av[j] = ((const float4*)vp)[j];
            sc = lookups[(size_t)(row0 + ar) * L_DIM + (kt >> 2)];
        } else {            // bias tile: A-columns = lookups (k-local 0..15), else 0
            sc = 1.f;
            if ((tid & 3) == 0) {
                const float* lp = lookups + (size_t)(row0 + ar) * L_DIM;
#pragma unroll
                for (int j = 0; j < 4; ++j) av[j] = ((const float4*)lp)[j];
            } else {
#pragma unroll
                for (int j = 0; j < 4; ++j) av[j] = (float4){0.f, 0.f, 0.f, 0.f};
            }
        }
    };

    auto writeA = [&](int bsel_) {
        float f[16] = {av[0].x, av[0].y, av[0].z, av[0].w,
                       av[1].x, av[1].y, av[1].z, av[1].w,
                       av[2].x, av[2].y, av[2].z, av[2].w,
                       av[3].x, av[3].y, av[3].z, av[3].w};
        uint32_t p[8];
#pragma unroll
        for (int k = 0; k < 8; ++k)
            p[k] = (uint32_t)f2bf(f[2 * k] * sc) | ((uint32_t)f2bf(f[2 * k + 1] * sc) << 16);
        char* abase = smem + bsel_ * 49152;
        uint4 q0 = {p[0], p[1], p[2], p[3]};
        uint4 q1 = {p[4], p[5], p[6], p[7]};
        int base = ar * 128 + akk * 2;
        int x    = (ar & 7) << 4;
        *(uint4*)(abase + ((base) ^ x))      = q0;
        *(uint4*)(abase + ((base + 16) ^ x)) = q1;
    };

    auto compute = [&](int bsel_) {
        char* base = smem + bsel_ * 49152;
#pragma unroll
        for (int ks = 0; ks < 2; ++ks) {
            const int kk2 = (kkl + ks * 32) * 2;
            bf16x8 af[4], bfr[4];
#pragma unroll
            for (int mt = 0; mt < 4; ++mt) {
                int row = arow + mt * 16;
                af[mt] = *(bf16x8*)(base + ((row * 128 + kk2) ^ ((row & 7) << 4)));
            }
#pragma unroll
            for (int nt = 0; nt < 4; ++nt) {
                int o = bcol + nt * 16;
                bfr[nt] = *(bf16x8*)(base + 16384 + ((o * 128 + kk2) ^ ((o & 7) << 4)));
            }
#pragma unroll
            for (int mt = 0; mt < 4; ++mt)
#pragma unroll
                for (int nt = 0; nt < 4; ++nt)
                    acc[mt][nt] = __builtin_amdgcn_mfma_f32_16x16x32_bf16(
                        af[mt], bfr[nt], acc[mt][nt], 0, 0, 0);
        }
    };

    // prologue: stage tile 0 into buffer 0
    stageB(0, 0);
    loadA(0);
    writeA(0);
    __syncthreads();   // drains vmcnt (global_load_lds) + lgkmcnt (ds_write)

    int bsel = 0;
    for (int kt = 0; kt < NKT; ++kt) {
        if (kt + 1 < NKT) {
            stageB(kt + 1, bsel ^ 1);
            loadA(kt + 1);
        }
        compute(bsel);
        if (kt + 1 < NKT) writeA(bsel ^ 1);
        __syncthreads();
        bsel ^= 1;
    }

    // epilogue: C/D layout col=lane&15, row=(lane>>4)*4+j  [m89]
    const int orow = row0 + wm * 64 + (lane >> 4) * 4;
    const int ocol = wn * 64 + (lane & 15);
#pragma unroll
    for (int mt = 0; mt < 4; ++mt)
#pragma unroll
        for (int nt = 0; nt < 4; ++nt) {
#pragma unroll
            for (int j = 0; j < 4; ++j)
                out[(size_t)(orow + mt * 16 + j) * O_DIM + ocol + nt * 16] = acc[mt][nt][j];
        }
}

extern "C" void kernel_launch(void* const* d_in, const int* in_sizes, int n_in,
                              void* d_out, int out_size, void* d_ws, size_t ws_size,
                              hipStream_t stream) {
    const float* lookups = (const float*)d_in[0];
    const float* values  = (const float*)d_in[1];
    const float* W       = (const float*)d_in[2];
    const float* bias    = (const float*)d_in[3];
    __hip_bfloat16* Wst  = (__hip_bfloat16*)d_ws;   // needs 65*32768 = 2.08 MB

    prep_w<<<dim3(4160), dim3(256), 0, stream>>>(W, bias, Wst);
    md_gemm<<<dim3(B_TOK / BM), dim3(THREADS), 0, stream>>>(lookups, values, Wst,
                                                            (float*)d_out);
}

// Round 2
// 231.711 us; speedup vs baseline: 1.3536x; 1.3536x over previous
//
#include <hip/hip_runtime.h>
#include <hip/hip_fp16.h>
#include <stdint.h>

// out[b,o] = sum_{l,i} lookups[b,l]*values[b,i]*W[l,i,o] + sum_l lookups[b,l]*bias[l,o]
// GEMM M=65536, K=64 tiles of 64 (i-outer, l-inner) + 1 bias tile, N=256. fp16 MFMA.

#define B_TOK 65536
#define L_DIM 16
#define I_DIM 256
#define O_DIM 256
#define NKT   65          // 64 K-tiles (ichunk*16 + l) + 1 bias tile
#define BM    256
#define BN    256
#define BK    64
#define THREADS 512

typedef __attribute__((ext_vector_type(8))) _Float16 f16x8;
typedef __attribute__((ext_vector_type(4))) float f32x4;

typedef __attribute__((address_space(3))) void      lds_void_t;
typedef const __attribute__((address_space(1))) void gbl_void_t;

// ---------------------------------------------------------------------------
// prep_w: build Wst = 65 tiles x 32KB fp16, B-transposed [o][kk], pre-swizzled:
// byte offset within tile = o*128 + ((c ^ (o&7))*16) + 2*j  where kk = c*8+j.
// Tile t<64: l = t&15, ibase = (t>>4)*64, element = W[l][ibase+kk][o].
// Tile 64:   element = (kk<16) ? bias[kk][o] : 0.
// Reads coalesced (256 consecutive o per instr); each thread writes its own
// 128B output row as 8x16B chunks (permuted in-row by the swizzle).
// ---------------------------------------------------------------------------
__global__ void prep_w(const float* __restrict__ W, const float* __restrict__ bias,
                       unsigned short* __restrict__ ws) {
    const int t = blockIdx.x;      // 0..64
    const int o = threadIdx.x;     // 0..255
    char* dstRow = (char*)(ws + (size_t)t * 16384) + o * 128;
    if (t < 64) {
        const int l = t & 15, ibase = (t >> 4) * 64;
        const float* src = W + ((size_t)l * I_DIM + ibase) * O_DIM + o;
#pragma unroll
        for (int c = 0; c < 8; ++c) {
            uint32_t p[4];
#pragma unroll
            for (int jp = 0; jp < 4; ++jp) {
                float a = src[(size_t)(c * 8 + 2 * jp) * O_DIM];
                float b = src[(size_t)(c * 8 + 2 * jp + 1) * O_DIM];
                p[jp] = __builtin_bit_cast(uint32_t, __floats2half2_rn(a, b));
            }
            uint4 q = {p[0], p[1], p[2], p[3]};
            *(uint4*)(dstRow + ((c ^ (o & 7)) * 16)) = q;
        }
    } else {
#pragma unroll
        for (int c = 0; c < 8; ++c) {
            uint32_t p[4] = {0u, 0u, 0u, 0u};
            if (c < 2) {
#pragma unroll
                for (int jp = 0; jp < 4; ++jp) {
                    int kk = c * 8 + 2 * jp;
                    float a = bias[(size_t)kk * O_DIM + o];
                    float b = bias[(size_t)(kk + 1) * O_DIM + o];
                    p[jp] = __builtin_bit_cast(uint32_t, __floats2half2_rn(a, b));
                }
            }
            uint4 q = {p[0], p[1], p[2], p[3]};
            *(uint4*)(dstRow + ((c ^ (o & 7)) * 16)) = q;
        }
    }
}

// ---------------------------------------------------------------------------
// md_gemm: 256 blocks (M/256), 512 threads = 8 waves (2M x 4N), wave tile 128x64.
// LDS per buffer: A[256][64] fp16 (32KB, XOR-swizzled, reg-staged via pk_mul) +
// B[256][64] fp16 (32KB, pre-swizzled in global, linear global_load_lds).
// Double-buffered: 128KB. K order: i-chunk outer (values in regs 16 kt), l inner.
// ---------------------------------------------------------------------------
__launch_bounds__(THREADS, 2)
__global__ void md_gemm(const float* __restrict__ lookups,        // [B][16]
                        const float* __restrict__ values,         // [B][256]
                        const unsigned short* __restrict__ Wst,   // [65][16384]
                        float* __restrict__ out) {                // [B][256]
    __shared__ char smem[2 * 65536];   // 128KB

    const int tid  = threadIdx.x;
    const int wid  = tid >> 6;
    const int lane = tid & 63;
    const int row0 = blockIdx.x * BM;

    // A staging ownership: row r, k-half h (32 k's = 16 half2)
    const int r = tid >> 1;          // 0..255
    const int h = tid & 1;

    // compute coords
    const int wm   = wid >> 2;       // 0..1
    const int wn   = wid & 3;        // 0..3
    const int arow = wm * 128 + (lane & 15);
    const int bcol = wn * 64  + (lane & 15);
    const int kkl  = (lane >> 4) * 8;

    f32x4 acc[8][4];
#pragma unroll
    for (int m = 0; m < 8; ++m)
#pragma unroll
        for (int n = 0; n < 4; ++n) acc[m][n] = (f32x4){0.f, 0.f, 0.f, 0.f};

    __half2 hvv[16];   // this thread's A source slice (fp16), current i-chunk

    auto stageB = [&](int kt, int nb) {
        const char* src = (const char*)Wst + (size_t)kt * 32768 + wid * 1024 + lane * 16;
        char* dst = smem + nb * 65536 + 32768 + wid * 1024;   // wave-uniform base
#pragma unroll
        for (int s = 0; s < 4; ++s)
            __builtin_amdgcn_global_load_lds((gbl_void_t*)(src + s * 8192),
                                             (lds_void_t*)(dst + s * 8192), 16, 0, 0);
    };

    auto prepA = [&](int kt) {
        if (kt < 64) {
            if ((kt & 15) == 0) {   // new i-chunk: refill values regs
                const float4* vp = (const float4*)(values + (size_t)(row0 + r) * I_DIM
                                                   + (kt >> 4) * 64 + h * 32);
#pragma unroll
                for (int j = 0; j < 8; ++j) {
                    float4 f = vp[j];
                    hvv[2 * j]     = __floats2half2_rn(f.x, f.y);
                    hvv[2 * j + 1] = __floats2half2_rn(f.z, f.w);
                }
            }
        } else {                    // bias tile: A columns = lookups (k<16), else 0
            if (h == 0) {
                const float4* lp = (const float4*)(lookups + (size_t)(row0 + r) * L_DIM);
#pragma unroll
                for (int j = 0; j < 4; ++j) {
                    float4 f = lp[j];
                    hvv[2 * j]     = __floats2half2_rn(f.x, f.y);
                    hvv[2 * j + 1] = __floats2half2_rn(f.z, f.w);
                }
#pragma unroll
                for (int j = 8; j < 16; ++j) hvv[j] = __floats2half2_rn(0.f, 0.f);
            } else {
#pragma unroll
                for (int j = 0; j < 16; ++j) hvv[j] = __floats2half2_rn(0.f, 0.f);
            }
        }
    };

    auto writeA = [&](int nb, float sc) {
        __half2 s2 = __float2half2_rn(sc);
        uint32_t p[16];
#pragma unroll
        for (int i = 0; i < 16; ++i)
            p[i] = __builtin_bit_cast(uint32_t, __hmul2(hvv[i], s2));
        char* abase = smem + nb * 65536;
#pragma unroll
        for (int w = 0; w < 4; ++w) {
            uint4 q = {p[4 * w], p[4 * w + 1], p[4 * w + 2], p[4 * w + 3]};
            *(uint4*)(abase + ((r * 128 + h * 64 + w * 16) ^ ((r & 7) << 4))) = q;
        }
    };

    auto compute = [&](int bs) {
        char* abase = smem + bs * 65536;
        char* bbase = abase + 32768;
#pragma unroll
        for (int ks = 0; ks < 2; ++ks) {
            const int kk2 = kkl * 2 + ks * 64;
            f16x8 af[8], bfr[4];
#pragma unroll
            for (int nt = 0; nt < 4; ++nt) {
                int o = bcol + nt * 16;
                bfr[nt] = *(f16x8*)(bbase + ((o * 128 + kk2) ^ ((o & 7) << 4)));
            }
#pragma unroll
            for (int mt = 0; mt < 8; ++mt) {
                int row = arow + mt * 16;
                af[mt] = *(f16x8*)(abase + ((row * 128 + kk2) ^ ((row & 7) << 4)));
            }
#pragma unroll
            for (int mt = 0; mt < 8; ++mt)
#pragma unroll
                for (int nt = 0; nt < 4; ++nt)
                    acc[mt][nt] = __builtin_amdgcn_mfma_f32_16x16x32_f16(
                        af[mt], bfr[nt], acc[mt][nt], 0, 0, 0);
        }
    };

    // prologue
    stageB(0, 0);
    prepA(0);
    {
        float lk0 = lookups[(size_t)(row0 + r) * L_DIM];   // l = 0
        writeA(0, lk0);
    }
    __syncthreads();   // drains vmcnt (global_load_lds) + lgkmcnt (ds_write)

    int bsel = 0;
    for (int kt = 0; kt < NKT; ++kt) {
        float lkn = 0.f;
        if (kt + 1 < NKT) {
            stageB(kt + 1, bsel ^ 1);
            prepA(kt + 1);
            lkn = (kt + 1 < 64) ? lookups[(size_t)(row0 + r) * L_DIM + ((kt + 1) & 15)]
                                : 1.0f;
        }
        compute(bsel);
        if (kt + 1 < NKT) writeA(bsel ^ 1, lkn);
        __syncthreads();
        bsel ^= 1;
    }

    // epilogue: C/D layout col=lane&15, row=(lane>>4)*4+j  [m89]
    const int orow = row0 + wm * 128 + (lane >> 4) * 4;
    const int ocol = wn * 64 + (lane & 15);
#pragma unroll
    for (int mt = 0; mt < 8; ++mt)
#pragma unroll
        for (int nt = 0; nt < 4; ++nt) {
#pragma unroll
            for (int j = 0; j < 4; ++j)
                out[(size_t)(orow + mt * 16 + j) * O_DIM + ocol + nt * 16] = acc[mt][nt][j];
        }
}

extern "C" void kernel_launch(void* const* d_in, const int* in_sizes, int n_in,
                              void* d_out, int out_size, void* d_ws, size_t ws_size,
                              hipStream_t stream) {
    const float* lookups = (const float*)d_in[0];
    const float* values  = (const float*)d_in[1];
    const float* W       = (const float*)d_in[2];
    const float* bias    = (const float*)d_in[3];
    unsigned short* Wst  = (unsigned short*)d_ws;   // 65*32768 B = 2.08 MB

    prep_w<<<dim3(NKT), dim3(256), 0, stream>>>(W, bias, Wst);
    md_gemm<<<dim3(B_TOK / BM), dim3(THREADS), 0, stream>>>(lookups, values, Wst,
                                                            (float*)d_out);
}